// Round 13
// baseline (430.347 us; speedup 1.0000x reference)
//
#include <hip/hip_runtime.h>
#include <hip/hip_bf16.h>
#include <math.h>

// ---------------------------------------------------------------------------
// GATv2 3-layer GNN. CSR-by-dst on-device (parallel scan); f16 MFMA GEMMs
// with double-buffered LDS staging of W; fused max-free-softmax attention
// (8-edge batched for gather MLP, packed-f16 logits+accumulator, index
// prefetch); BN/ReLU/residual epilogue fused. Layer-1 output f16-only.
// ---------------------------------------------------------------------------

using h16     = _Float16;
using half2v  = __attribute__((ext_vector_type(2))) h16;
using half4v  = __attribute__((ext_vector_type(4))) h16;
using half8   = __attribute__((ext_vector_type(8))) h16;
using floatx4 = __attribute__((ext_vector_type(4))) float;

__device__ __forceinline__ float lrelu(float x) { return x > 0.f ? x : 0.2f * x; }

__device__ __forceinline__ half2v shfl_xor_h2(half2v v, int mask) {
    float f = __builtin_bit_cast(float, v);
    f = __shfl_xor(f, mask, 64);
    return __builtin_bit_cast(half2v, f);
}

// ---------------- CSR build ----------------
__global__ void hist_dst(const int* __restrict__ ei, int E, int* __restrict__ deg) {
    int e = blockIdx.x * blockDim.x + threadIdx.x;
    if (e < E) atomicAdd(&deg[ei[E + e]], 1);
}

__global__ __launch_bounds__(256) void scan_blk(const int* __restrict__ deg,
                                                int* __restrict__ rowstart,
                                                int* __restrict__ bsum, int N) {
    int t = blockIdx.x * 256 + threadIdx.x;
    int lane = threadIdx.x & 63, wid = threadIdx.x >> 6;
    int v = (t < N) ? deg[t] : 0;
    int x = v;
#pragma unroll
    for (int off = 1; off < 64; off <<= 1) {
        int y = __shfl_up(x, off, 64);
        if (lane >= off) x += y;
    }
    __shared__ int wsum[4];
    if (lane == 63) wsum[wid] = x;
    __syncthreads();
    int add = 0;
#pragma unroll
    for (int w = 0; w < 4; ++w) if (w < wid) add += wsum[w];
    int incl = x + add;
    if (t < N) rowstart[t] = incl - v;
    if (threadIdx.x == 255) bsum[blockIdx.x] = incl;
}

__global__ __launch_bounds__(256) void scan_off(int* __restrict__ bsum, int NB) {
    int t = threadIdx.x;
    int lane = t & 63, wid = t >> 6;
    int v = (t < NB) ? bsum[t] : 0;
    int x = v;
#pragma unroll
    for (int off = 1; off < 64; off <<= 1) {
        int y = __shfl_up(x, off, 64);
        if (lane >= off) x += y;
    }
    __shared__ int wsum[4];
    if (lane == 63) wsum[wid] = x;
    __syncthreads();
    int add = 0;
#pragma unroll
    for (int w = 0; w < 4; ++w) if (w < wid) add += wsum[w];
    if (t < NB) bsum[t] = x + add - v;
}

__global__ void add_off(const int* __restrict__ bsum, int* __restrict__ rowstart,
                        int* __restrict__ cursor, int N) {
    int t = blockIdx.x * 256 + threadIdx.x;
    if (t >= N) return;
    int r = rowstart[t] + bsum[blockIdx.x];
    rowstart[t] = r;
    cursor[t] = r;
}

__global__ void scatter_src(const int* __restrict__ ei, int E,
                            int* __restrict__ cursor, int* __restrict__ csr_src) {
    int e = blockIdx.x * blockDim.x + threadIdx.x;
    if (e >= E) return;
    int d = ei[E + e];
    int pos = atomicAdd(&cursor[d], 1);
    csr_src[pos] = ei[e];
}

// ------- weight packing + x conversion + deg zeroing (one launch) ---------
__device__ __forceinline__ void pack_one(const float* __restrict__ W,
                                         h16* __restrict__ Wp,
                                         int t, int K, int NC) {
    int j = t & 7;
    int l = (t >> 3) & 63;
    int rest = t >> 9;
    int NT = NC >> 4;
    int nt = rest % NT;
    int kc = rest / NT;
    int row = kc * 32 + (l >> 4) * 8 + j;
    int col = nt * 16 + (l & 15);
    Wp[t] = (h16)W[(size_t)row * NC + col];
}

__global__ void pack_all(const float* __restrict__ W_in,
                         const float* __restrict__ Wl0, const float* __restrict__ Wr0,
                         const float* __restrict__ Wl1, const float* __restrict__ Wr1,
                         h16* __restrict__ P_in,
                         h16* __restrict__ P_l0, h16* __restrict__ P_r0,
                         h16* __restrict__ P_l1, h16* __restrict__ P_r1,
                         const float4* __restrict__ x, half4v* __restrict__ xh, int n4,
                         int* __restrict__ deg, int N) {
    int t = blockIdx.x * blockDim.x + threadIdx.x;
    if (t < 8192)        pack_one(W_in, P_in, t, 128, 64);
    else if (t < 24576)  pack_one(Wl0, P_l0, t - 8192, 64, 256);
    else if (t < 40960)  pack_one(Wr0, P_r0, t - 24576, 64, 256);
    else if (t < 106496) pack_one(Wl1, P_l1, t - 40960, 256, 256);
    else if (t < 172032) pack_one(Wr1, P_r1, t - 106496, 256, 256);
    else if (t < 172032 + n4) {
        int u = t - 172032;
        float4 v = x[u];
        half4v o = { (h16)v.x, (h16)v.y, (h16)v.z, (h16)v.w };
        xh[u] = o;
    } else {
        int u = t - 172032 - n4;
        if (u < N) deg[u] = 0;
    }
}

// --------- MFMA GEMM, double-buffered LDS staging of W -----------------
template<int KC, int NT, bool RELU, bool DUAL>
__global__ __launch_bounds__(256) void gemm_lds(
        const h16* __restrict__ Xh,
        const h16* __restrict__ Wp0, const h16* __restrict__ Wp1,
        const float* __restrict__ bias,
        h16* __restrict__ out0, h16* __restrict__ out1, int M) {
    constexpr int K = KC * 32;
    constexpr int ldo = NT * 16;
    constexpr int CHUNK8 = NT * 64;
    constexpr int PER_THR = CHUNK8 / 256;
    __shared__ half8 wbuf[2][CHUNK8];

    const h16* Wp = (DUAL && blockIdx.y) ? Wp1 : Wp0;
    h16* out = (DUAL && blockIdx.y) ? out1 : out0;
    const half8* WG = (const half8*)Wp;

    const int tid = threadIdx.x;
    const int wid = tid >> 6, lane = tid & 63;
    const int quad = lane >> 4, li = lane & 15;
    const int r0 = blockIdx.x * 64 + wid * 16;
    int arow = r0 + li; if (arow >= M) arow = M - 1;
    const half8* A8 = (const half8*)Xh + (size_t)arow * (K / 8) + quad;

    floatx4 acc[NT];
#pragma unroll
    for (int t = 0; t < NT; ++t) acc[t] = (floatx4){0.f, 0.f, 0.f, 0.f};

    half8 st[PER_THR];
#pragma unroll
    for (int i = 0; i < PER_THR; ++i) st[i] = WG[i * 256 + tid];
#pragma unroll
    for (int i = 0; i < PER_THR; ++i) wbuf[0][i * 256 + tid] = st[i];
    __syncthreads();

#pragma unroll
    for (int kc = 0; kc < KC; ++kc) {
        int cur = kc & 1;
        if (kc + 1 < KC) {
#pragma unroll
            for (int i = 0; i < PER_THR; ++i)
                st[i] = WG[(size_t)(kc + 1) * CHUNK8 + i * 256 + tid];
        }
        half8 a = A8[kc * 4];
#pragma unroll
        for (int nt = 0; nt < NT; ++nt) {
            half8 b = wbuf[cur][nt * 64 + lane];
            acc[nt] = __builtin_amdgcn_mfma_f32_16x16x32_f16(a, b, acc[nt], 0, 0, 0);
        }
        if (kc + 1 < KC) {
#pragma unroll
            for (int i = 0; i < PER_THR; ++i) wbuf[cur ^ 1][i * 256 + tid] = st[i];
        }
        __syncthreads();
    }

#pragma unroll
    for (int nt = 0; nt < NT; ++nt) {
#pragma unroll
        for (int reg = 0; reg < 4; ++reg) {
            int rr = r0 + quad * 4 + reg;
            if (rr >= M) continue;
            float v = acc[nt][reg];
            if (RELU) v = fmaxf(v + bias[nt * 16 + li], 0.f);
            out[(size_t)rr * ldo + nt * 16 + li] = (h16)v;
        }
    }
}

// ---- fused 4-head attention + BN + ReLU (+residual), wave/dst, f16 in -----
// Max-free softmax; 8-edge batch (gather MLP); f16 packed logits+accumulator.
__global__ void attn4_bn(int N, const h16* __restrict__ XL, const h16* __restrict__ XR,
                         const float* __restrict__ att,
                         const int* __restrict__ rowstart, const int* __restrict__ deg,
                         const int* __restrict__ csr_src,
                         const float* __restrict__ gamma, const float* __restrict__ beta,
                         const float* __restrict__ mean, const float* __restrict__ var,
                         const float* __restrict__ bias, const float* __restrict__ resid,
                         float* __restrict__ out, h16* __restrict__ outb) {
    int d = blockIdx.x * (blockDim.x >> 6) + (threadIdx.x >> 6);
    int lane = threadIdx.x & 63;
    if (d >= N) return;
    half4v bv = *(const half4v*)(XR + (size_t)d * 256 + lane * 4);
    float4 wf = ((const float4*)att)[lane];
    half2v b0 = bv.xy, b1 = bv.zw;
    half2v w0 = { (h16)wf.x, (h16)wf.y };
    half2v w1 = { (h16)wf.z, (h16)wf.w };
    const h16 k02 = (h16)0.2f;

    auto edge_part = [&](half4v xv) -> h16 {
        half2v e0 = xv.xy + b0, e1 = xv.zw + b1;
        half2v l0 = __builtin_elementwise_max(e0, e0 * k02);
        half2v l1 = __builtin_elementwise_max(e1, e1 * k02);
        half2v qd = l0 * w0 + l1 * w1;
        return qd.x + qd.y;
    };

    // self-loop
    half4v av = *(const half4v*)(XL + (size_t)d * 256 + lane * 4);
    float p = (float)edge_part(av);
    p += __shfl_xor(p, 1, 64); p += __shfl_xor(p, 2, 64);
    p += __shfl_xor(p, 4, 64); p += __shfl_xor(p, 8, 64);
    float es = __expf(p);
    float l = es;
    h16 eh = (h16)es;
    half2v ebc = { eh, eh };
    half2v acc0 = ebc * av.xy;
    half2v acc1 = ebc * av.zw;

    int start = rowstart[d], n = deg[d];
    int nm1 = n - 1;
    int t0 = 0, t1 = 0, t2 = 0, t3 = 0, t4 = 0, t5 = 0, t6 = 0, t7 = 0;
    if (n > 0) {
        t0 = csr_src[start];
        t1 = csr_src[start + min(1, nm1)];
        t2 = csr_src[start + min(2, nm1)];
        t3 = csr_src[start + min(3, nm1)];
        t4 = csr_src[start + min(4, nm1)];
        t5 = csr_src[start + min(5, nm1)];
        t6 = csr_src[start + min(6, nm1)];
        t7 = csr_src[start + min(7, nm1)];
    }
    for (int i = 0; i < n; i += 8) {
        half4v x0 = *(const half4v*)(XL + (size_t)t0 * 256 + lane * 4);
        half4v x1 = *(const half4v*)(XL + (size_t)t1 * 256 + lane * 4);
        half4v x2 = *(const half4v*)(XL + (size_t)t2 * 256 + lane * 4);
        half4v x3 = *(const half4v*)(XL + (size_t)t3 * 256 + lane * 4);
        half4v x4 = *(const half4v*)(XL + (size_t)t4 * 256 + lane * 4);
        half4v x5 = *(const half4v*)(XL + (size_t)t5 * 256 + lane * 4);
        half4v x6 = *(const half4v*)(XL + (size_t)t6 * 256 + lane * 4);
        half4v x7 = *(const half4v*)(XL + (size_t)t7 * 256 + lane * 4);
        int j = i + 8;
        if (j < n) {                 // prefetch next batch's indices
            t0 = csr_src[start + j];
            t1 = csr_src[start + min(j + 1, nm1)];
            t2 = csr_src[start + min(j + 2, nm1)];
            t3 = csr_src[start + min(j + 3, nm1)];
            t4 = csr_src[start + min(j + 4, nm1)];
            t5 = csr_src[start + min(j + 5, nm1)];
            t6 = csr_src[start + min(j + 6, nm1)];
            t7 = csr_src[start + min(j + 7, nm1)];
        }
        half2v p01 = { edge_part(x0), edge_part(x1) };
        half2v p23 = { edge_part(x2), edge_part(x3) };
        half2v p45 = { edge_part(x4), edge_part(x5) };
        half2v p67 = { edge_part(x6), edge_part(x7) };
#pragma unroll
        for (int s = 1; s < 16; s <<= 1) {
            p01 += shfl_xor_h2(p01, s);
            p23 += shfl_xor_h2(p23, s);
            p45 += shfl_xor_h2(p45, s);
            p67 += shfl_xor_h2(p67, s);
        }
        int rem = n - i;
        float e0 = __expf((float)p01.x);
        float e1 = (rem > 1) ? __expf((float)p01.y) : 0.f;
        float e2 = (rem > 2) ? __expf((float)p23.x) : 0.f;
        float e3 = (rem > 3) ? __expf((float)p23.y) : 0.f;
        float e4 = (rem > 4) ? __expf((float)p45.x) : 0.f;
        float e5 = (rem > 5) ? __expf((float)p45.y) : 0.f;
        float e6 = (rem > 6) ? __expf((float)p67.x) : 0.f;
        float e7 = (rem > 7) ? __expf((float)p67.y) : 0.f;
        l += ((e0 + e1) + (e2 + e3)) + ((e4 + e5) + (e6 + e7));
        h16 h0 = (h16)e0, h1 = (h16)e1, h2 = (h16)e2, h3 = (h16)e3;
        h16 h4 = (h16)e4, h5 = (h16)e5, h6 = (h16)e6, h7 = (h16)e7;
        half2v eb0 = { h0, h0 }, eb1 = { h1, h1 }, eb2 = { h2, h2 }, eb3 = { h3, h3 };
        half2v eb4 = { h4, h4 }, eb5 = { h5, h5 }, eb6 = { h6, h6 }, eb7 = { h7, h7 };
        acc0 += eb0 * x0.xy; acc1 += eb0 * x0.zw;
        acc0 += eb1 * x1.xy; acc1 += eb1 * x1.zw;
        acc0 += eb2 * x2.xy; acc1 += eb2 * x2.zw;
        acc0 += eb3 * x3.xy; acc1 += eb3 * x3.zw;
        acc0 += eb4 * x4.xy; acc1 += eb4 * x4.zw;
        acc0 += eb5 * x5.xy; acc1 += eb5 * x5.zw;
        acc0 += eb6 * x6.xy; acc1 += eb6 * x6.zw;
        acc0 += eb7 * x7.xy; acc1 += eb7 * x7.zw;
    }
    float4 acc = { (float)acc0.x, (float)acc0.y, (float)acc1.x, (float)acc1.y };
    float inv = 1.f / l;
    float4 g  = ((const float4*)gamma)[lane];
    float4 be = ((const float4*)beta)[lane];
    float4 mu = ((const float4*)mean)[lane];
    float4 va = ((const float4*)var)[lane];
    float4 bi = ((const float4*)bias)[lane];
    float4 sc4, sh4;
    sc4.x = g.x * rsqrtf(va.x + 1e-5f); sh4.x = (bi.x - mu.x) * sc4.x + be.x;
    sc4.y = g.y * rsqrtf(va.y + 1e-5f); sh4.y = (bi.y - mu.y) * sc4.y + be.y;
    sc4.z = g.z * rsqrtf(va.z + 1e-5f); sh4.z = (bi.z - mu.z) * sc4.z + be.z;
    sc4.w = g.w * rsqrtf(va.w + 1e-5f); sh4.w = (bi.w - mu.w) * sc4.w + be.w;
    float4 o;
    o.x = fmaxf(acc.x * inv * sc4.x + sh4.x, 0.f);
    o.y = fmaxf(acc.y * inv * sc4.y + sh4.y, 0.f);
    o.z = fmaxf(acc.z * inv * sc4.z + sh4.z, 0.f);
    o.w = fmaxf(acc.w * inv * sc4.w + sh4.w, 0.f);
    if (resid) {
        float4 rv = *(const float4*)(resid + (size_t)d * 256 + lane * 4);
        o.x += rv.x; o.y += rv.y; o.z += rv.z; o.w += rv.w;
    }
    if (out) *(float4*)(out + (size_t)d * 256 + lane * 4) = o;
    if (outb) {
        half4v ob = { (h16)o.x, (h16)o.y, (h16)o.z, (h16)o.w };
        *(half4v*)(outb + (size_t)d * 256 + lane * 4) = ob;
    }
}

// ---- layer 2 projections from f16 input: 16 lanes/node, K=256 ----
__global__ void gemm2_wave(const h16* __restrict__ X, const float* __restrict__ Wl,
                           const float* __restrict__ Wr, float* __restrict__ xl2,
                           float* __restrict__ xr2, int N) {
    int t = blockIdx.x * blockDim.x + threadIdx.x;
    int n = t >> 4;
    int sl = t & 15;
    if (n >= N) return;
    const half4v* Xr = (const half4v*)(X + (size_t)n * 256);
    const float4* Wl4 = (const float4*)Wl;
    const float4* Wr4 = (const float4*)Wr;
    float l0 = 0.f, l1 = 0.f, r0 = 0.f, r1 = 0.f;
#pragma unroll
    for (int j = 0; j < 4; ++j) {
        int idx = sl + j * 16;
        half4v xh = Xr[idx];
        float4 xv = { (float)xh.x, (float)xh.y, (float)xh.z, (float)xh.w };
        float4 wa = Wl4[idx * 2];
        float4 wb = Wl4[idx * 2 + 1];
        l0 += xv.x * wa.x + xv.y * wa.z + xv.z * wb.x + xv.w * wb.z;
        l1 += xv.x * wa.y + xv.y * wa.w + xv.z * wb.y + xv.w * wb.w;
        wa = Wr4[idx * 2]; wb = Wr4[idx * 2 + 1];
        r0 += xv.x * wa.x + xv.y * wa.z + xv.z * wb.x + xv.w * wb.z;
        r1 += xv.x * wa.y + xv.y * wa.w + xv.z * wb.y + xv.w * wb.w;
    }
#pragma unroll
    for (int off = 1; off < 16; off <<= 1) {
        l0 += __shfl_xor(l0, off, 64);
        l1 += __shfl_xor(l1, off, 64);
        r0 += __shfl_xor(r0, off, 64);
        r1 += __shfl_xor(r1, off, 64);
    }
    if (sl == 0) {
        xl2[n * 2] = l0; xl2[n * 2 + 1] = l1;
        xr2[n * 2] = r0; xr2[n * 2 + 1] = r1;
    }
}

// ---- fused layer-2 attention (1 head, C=2) + log_softmax, 16 lanes/dst ----
__global__ void attn1_16(int N, const float* __restrict__ xl2, const float* __restrict__ xr2,
                         const float* __restrict__ att, const float* __restrict__ bias,
                         const int* __restrict__ rowstart, const int* __restrict__ deg,
                         const int* __restrict__ csr_src, float* __restrict__ out) {
    int t = blockIdx.x * blockDim.x + threadIdx.x;
    int d = t >> 4, sl = t & 15;
    if (d >= N) return;
    float a0 = att[0], a1 = att[1];
    float2 xr = ((const float2*)xr2)[d];
    float b0 = xr.x, b1 = xr.y;
    float l = 0.f, ac0 = 0.f, ac1 = 0.f;
    int st = rowstart[d], n = deg[d];
    if (sl == 0) {
        float2 s = ((const float2*)xl2)[d];
        float p = lrelu(s.x + b0) * a0 + lrelu(s.y + b1) * a1;
        float e = __expf(p);
        l = e; ac0 = e * s.x; ac1 = e * s.y;
    }
    for (int i = sl; i < n; i += 16) {
        int s = csr_src[st + i];
        float2 xv = ((const float2*)xl2)[s];
        float q = lrelu(xv.x + b0) * a0 + lrelu(xv.y + b1) * a1;
        float e = __expf(q);
        l += e; ac0 += e * xv.x; ac1 += e * xv.y;
    }
#pragma unroll
    for (int off = 1; off < 16; off <<= 1) {
        l   += __shfl_xor(l, off, 64);
        ac0 += __shfl_xor(ac0, off, 64);
        ac1 += __shfl_xor(ac1, off, 64);
    }
    if (sl == 0) {
        float inv = 1.f / l;
        float v0 = ac0 * inv + bias[0];
        float v1 = ac1 * inv + bias[1];
        float mx = fmaxf(v0, v1);
        float lse = mx + logf(__expf(v0 - mx) + __expf(v1 - mx));
        out[d * 2] = v0 - lse;
        out[d * 2 + 1] = v1 - lse;
    }
}

extern "C" void kernel_launch(void* const* d_in, const int* in_sizes, int n_in,
                              void* d_out, int out_size, void* d_ws, size_t ws_size,
                              hipStream_t stream) {
    const float* x        = (const float*)d_in[0];
    const int*   ei       = (const int*)  d_in[1];
    const float* W_in     = (const float*)d_in[2];
    const float* b_in     = (const float*)d_in[3];
    const float* Wl0      = (const float*)d_in[4];
    const float* Wr0      = (const float*)d_in[5];
    const float* att0     = (const float*)d_in[6];
    const float* bias0    = (const float*)d_in[7];
    const float* Wl1      = (const float*)d_in[8];
    const float* Wr1      = (const float*)d_in[9];
    const float* att1     = (const float*)d_in[10];
    const float* bias1    = (const float*)d_in[11];
    const float* Wl2      = (const float*)d_in[12];
    const float* Wr2      = (const float*)d_in[13];
    const float* att2     = (const float*)d_in[14];
    const float* bias2    = (const float*)d_in[15];
    const float* bn_gamma = (const float*)d_in[16];
    const float* bn_beta  = (const float*)d_in[17];
    const float* bn_mean  = (const float*)d_in[18];
    const float* bn_var   = (const float*)d_in[19];

    const int N  = in_sizes[0] / 128;
    const int E  = in_sizes[1] / 2;
    const int NB = (N + 255) / 256;

    float* ws = (float*)d_ws;
    size_t off = 0;
    float* C    = ws + off; off += (size_t)N * 256;     // layer0 out / residual (f32)
    float* XL2  = ws + off; off += (size_t)N * 2;
    float* XR2  = ws + off; off += (size_t)N * 2;
    h16* Ah   = (h16*)(ws + off); off += (size_t)N * 128;  // f16 xl [N,256]
    h16* Bh   = (h16*)(ws + off); off += (size_t)N * 128;  // f16 xr [N,256]
    h16* Ch   = (h16*)(ws + off); off += (size_t)N * 128;  // f16 copy of C
    h16* Dh   = (h16*)(ws + off); off += (size_t)N * 128;  // f16 layer1 out
    h16* H0h  = (h16*)(ws + off); off += (size_t)N * 32;   // f16 h0 [N,64]
    h16* xh   = (h16*)(ws + off); off += (size_t)N * 64;   // f16 x  [N,128]
    h16* Wp_in = (h16*)(ws + off); off += 4096;    // 128*64
    h16* Wp_l0 = (h16*)(ws + off); off += 8192;    // 64*256
    h16* Wp_r0 = (h16*)(ws + off); off += 8192;
    h16* Wp_l1 = (h16*)(ws + off); off += 32768;   // 256*256
    h16* Wp_r1 = (h16*)(ws + off); off += 32768;
    int* ip = (int*)(ws + off);
    int* deg      = ip;              ip += N;
    int* rowstart = ip;              ip += N;
    int* cursor   = ip;              ip += N;
    int* bsum     = ip;              ip += NB;
    int* csr_src  = ip;              ip += E;

    // ---- weight packing + x conversion + deg zeroing (one launch) ----
    const int PACK_T = 172032 + N * 32 + N;
    pack_all<<<(PACK_T + 255) / 256, 256, 0, stream>>>(
        W_in, Wl0, Wr0, Wl1, Wr1, Wp_in, Wp_l0, Wp_r0, Wp_l1, Wp_r1,
        (const float4*)x, (half4v*)xh, N * 32, deg, N);

    // ---- CSR build (parallel scan) ----
    hist_dst<<<(E + 255) / 256, 256, 0, stream>>>(ei, E, deg);
    scan_blk<<<NB, 256, 0, stream>>>(deg, rowstart, bsum, N);
    scan_off<<<1, 256, 0, stream>>>(bsum, NB);
    add_off<<<NB, 256, 0, stream>>>(bsum, rowstart, cursor, N);
    scatter_src<<<(E + 255) / 256, 256, 0, stream>>>(ei, E, cursor, csr_src);

    const int GBM = (N + 63) / 64;

    // h0 = relu(x @ W_in + b_in)  -> f16
    gemm_lds<4, 4, true, false><<<GBM, 256, 0, stream>>>(
        xh, Wp_in, nullptr, b_in, H0h, nullptr, N);

    // -------- layer 0 --------
    gemm_lds<2, 16, false, true><<<dim3(GBM, 2), 256, 0, stream>>>(
        H0h, Wp_l0, Wp_r0, nullptr, Ah, Bh, N);
    attn4_bn<<<(N + 3) / 4, 256, 0, stream>>>(N, Ah, Bh, att0, rowstart, deg, csr_src,
                                              bn_gamma, bn_beta, bn_mean, bn_var,
                                              bias0, nullptr, C, Ch);

    // -------- layer 1 (residual) --------
    gemm_lds<8, 16, false, true><<<dim3(GBM, 2), 256, 0, stream>>>(
        Ch, Wp_l1, Wp_r1, nullptr, Ah, Bh, N);
    attn4_bn<<<(N + 3) / 4, 256, 0, stream>>>(N, Ah, Bh, att1, rowstart, deg, csr_src,
                                              bn_gamma + 256, bn_beta + 256, bn_mean + 256,
                                              bn_var + 256, bias1, C, nullptr, Dh);

    // -------- layer 2 (1 head, C=2) + log_softmax --------
    gemm2_wave<<<(N * 16 + 255) / 256, 256, 0, stream>>>(Dh, Wl2, Wr2, XL2, XR2, N);
    attn1_16<<<(N * 16 + 255) / 256, 256, 0, stream>>>(N, XL2, XR2, att2, bias2,
                                                       rowstart, deg, csr_src, (float*)d_out);
}

// Round 14
// 424.043 us; speedup vs baseline: 1.0149x; 1.0149x over previous
//
#include <hip/hip_runtime.h>
#include <hip/hip_bf16.h>
#include <math.h>

// ---------------------------------------------------------------------------
// GATv2 3-layer GNN. CSR-by-dst, padded to 4-edge batches with self-loop
// folded in (pad slots = dst row, masked); f16 MFMA GEMMs with double-
// buffered LDS staging; fused max-free-softmax attention (batch-4, int4
// index loads, packed-f16 logits+accumulator); BN/ReLU/residual fused.
// ---------------------------------------------------------------------------

using h16     = _Float16;
using half2v  = __attribute__((ext_vector_type(2))) h16;
using half4v  = __attribute__((ext_vector_type(4))) h16;
using half8   = __attribute__((ext_vector_type(8))) h16;
using floatx4 = __attribute__((ext_vector_type(4))) float;

__device__ __forceinline__ float lrelu(float x) { return x > 0.f ? x : 0.2f * x; }

__device__ __forceinline__ half2v shfl_xor_h2(half2v v, int mask) {
    float f = __builtin_bit_cast(float, v);
    f = __shfl_xor(f, mask, 64);
    return __builtin_bit_cast(half2v, f);
}

// ---------------- CSR build ----------------
__global__ void hist_dst(const int* __restrict__ ei, int E, int* __restrict__ deg) {
    int e = blockIdx.x * blockDim.x + threadIdx.x;
    if (e < E) atomicAdd(&deg[ei[E + e]], 1);
}

// padded row length = ceil((deg+1)/4)*4  (self-loop + pads)
__global__ __launch_bounds__(256) void scan_blk(const int* __restrict__ deg,
                                                int* __restrict__ rowstart,
                                                int* __restrict__ bsum, int N) {
    int t = blockIdx.x * 256 + threadIdx.x;
    int lane = threadIdx.x & 63, wid = threadIdx.x >> 6;
    int v = (t < N) ? ((deg[t] + 4) & ~3) : 0;
    int x = v;
#pragma unroll
    for (int off = 1; off < 64; off <<= 1) {
        int y = __shfl_up(x, off, 64);
        if (lane >= off) x += y;
    }
    __shared__ int wsum[4];
    if (lane == 63) wsum[wid] = x;
    __syncthreads();
    int add = 0;
#pragma unroll
    for (int w = 0; w < 4; ++w) if (w < wid) add += wsum[w];
    int incl = x + add;
    if (t < N) rowstart[t] = incl - v;
    if (threadIdx.x == 255) bsum[blockIdx.x] = incl;
}

__global__ __launch_bounds__(256) void scan_off(int* __restrict__ bsum, int NB) {
    int t = threadIdx.x;
    int lane = t & 63, wid = t >> 6;
    int v = (t < NB) ? bsum[t] : 0;
    int x = v;
#pragma unroll
    for (int off = 1; off < 64; off <<= 1) {
        int y = __shfl_up(x, off, 64);
        if (lane >= off) x += y;
    }
    __shared__ int wsum[4];
    if (lane == 63) wsum[wid] = x;
    __syncthreads();
    int add = 0;
#pragma unroll
    for (int w = 0; w < 4; ++w) if (w < wid) add += wsum[w];
    if (t < NB) bsum[t] = x + add - v;
}

// finalize rowstart/cursor; write self-loop + pad entries (= dst index)
__global__ void add_off(const int* __restrict__ bsum, const int* __restrict__ deg,
                        int* __restrict__ rowstart, int* __restrict__ cursor,
                        int* __restrict__ csr_src, int N) {
    int t = blockIdx.x * 256 + threadIdx.x;
    if (t >= N) return;
    int r = rowstart[t] + bsum[blockIdx.x];
    rowstart[t] = r;
    cursor[t] = r;
    int dg = deg[t];
    int npad = (dg + 4) & ~3;
    for (int k = dg; k < npad; ++k) csr_src[r + k] = t;
}

__global__ void scatter_src(const int* __restrict__ ei, int E,
                            int* __restrict__ cursor, int* __restrict__ csr_src) {
    int e = blockIdx.x * blockDim.x + threadIdx.x;
    if (e >= E) return;
    int d = ei[E + e];
    int pos = atomicAdd(&cursor[d], 1);
    csr_src[pos] = ei[e];
}

// ------- weight packing + x conversion + deg zeroing (one launch) ---------
__device__ __forceinline__ void pack_one(const float* __restrict__ W,
                                         h16* __restrict__ Wp,
                                         int t, int K, int NC) {
    int j = t & 7;
    int l = (t >> 3) & 63;
    int rest = t >> 9;
    int NT = NC >> 4;
    int nt = rest % NT;
    int kc = rest / NT;
    int row = kc * 32 + (l >> 4) * 8 + j;
    int col = nt * 16 + (l & 15);
    Wp[t] = (h16)W[(size_t)row * NC + col];
}

__global__ void pack_all(const float* __restrict__ W_in,
                         const float* __restrict__ Wl0, const float* __restrict__ Wr0,
                         const float* __restrict__ Wl1, const float* __restrict__ Wr1,
                         h16* __restrict__ P_in,
                         h16* __restrict__ P_l0, h16* __restrict__ P_r0,
                         h16* __restrict__ P_l1, h16* __restrict__ P_r1,
                         const float4* __restrict__ x, half4v* __restrict__ xh, int n4,
                         int* __restrict__ deg, int N) {
    int t = blockIdx.x * blockDim.x + threadIdx.x;
    if (t < 8192)        pack_one(W_in, P_in, t, 128, 64);
    else if (t < 24576)  pack_one(Wl0, P_l0, t - 8192, 64, 256);
    else if (t < 40960)  pack_one(Wr0, P_r0, t - 24576, 64, 256);
    else if (t < 106496) pack_one(Wl1, P_l1, t - 40960, 256, 256);
    else if (t < 172032) pack_one(Wr1, P_r1, t - 106496, 256, 256);
    else if (t < 172032 + n4) {
        int u = t - 172032;
        float4 v = x[u];
        half4v o = { (h16)v.x, (h16)v.y, (h16)v.z, (h16)v.w };
        xh[u] = o;
    } else {
        int u = t - 172032 - n4;
        if (u < N) deg[u] = 0;
    }
}

// --------- MFMA GEMM, double-buffered LDS staging of W -----------------
template<int KC, int NT, bool RELU, bool DUAL>
__global__ __launch_bounds__(256) void gemm_lds(
        const h16* __restrict__ Xh,
        const h16* __restrict__ Wp0, const h16* __restrict__ Wp1,
        const float* __restrict__ bias,
        h16* __restrict__ out0, h16* __restrict__ out1, int M) {
    constexpr int K = KC * 32;
    constexpr int ldo = NT * 16;
    constexpr int CHUNK8 = NT * 64;
    constexpr int PER_THR = CHUNK8 / 256;
    __shared__ half8 wbuf[2][CHUNK8];

    const h16* Wp = (DUAL && blockIdx.y) ? Wp1 : Wp0;
    h16* out = (DUAL && blockIdx.y) ? out1 : out0;
    const half8* WG = (const half8*)Wp;

    const int tid = threadIdx.x;
    const int wid = tid >> 6, lane = tid & 63;
    const int quad = lane >> 4, li = lane & 15;
    const int r0 = blockIdx.x * 64 + wid * 16;
    int arow = r0 + li; if (arow >= M) arow = M - 1;
    const half8* A8 = (const half8*)Xh + (size_t)arow * (K / 8) + quad;

    floatx4 acc[NT];
#pragma unroll
    for (int t = 0; t < NT; ++t) acc[t] = (floatx4){0.f, 0.f, 0.f, 0.f};

    half8 st[PER_THR];
#pragma unroll
    for (int i = 0; i < PER_THR; ++i) st[i] = WG[i * 256 + tid];
#pragma unroll
    for (int i = 0; i < PER_THR; ++i) wbuf[0][i * 256 + tid] = st[i];
    __syncthreads();

#pragma unroll
    for (int kc = 0; kc < KC; ++kc) {
        int cur = kc & 1;
        if (kc + 1 < KC) {
#pragma unroll
            for (int i = 0; i < PER_THR; ++i)
                st[i] = WG[(size_t)(kc + 1) * CHUNK8 + i * 256 + tid];
        }
        half8 a = A8[kc * 4];
#pragma unroll
        for (int nt = 0; nt < NT; ++nt) {
            half8 b = wbuf[cur][nt * 64 + lane];
            acc[nt] = __builtin_amdgcn_mfma_f32_16x16x32_f16(a, b, acc[nt], 0, 0, 0);
        }
        if (kc + 1 < KC) {
#pragma unroll
            for (int i = 0; i < PER_THR; ++i) wbuf[cur ^ 1][i * 256 + tid] = st[i];
        }
        __syncthreads();
    }

#pragma unroll
    for (int nt = 0; nt < NT; ++nt) {
#pragma unroll
        for (int reg = 0; reg < 4; ++reg) {
            int rr = r0 + quad * 4 + reg;
            if (rr >= M) continue;
            float v = acc[nt][reg];
            if (RELU) v = fmaxf(v + bias[nt * 16 + li], 0.f);
            out[(size_t)rr * ldo + nt * 16 + li] = (h16)v;
        }
    }
}

// ---- fused 4-head attention + BN + ReLU (+residual), wave/dst, f16 in -----
// Padded CSR (self-loop included): batch-4, one int4 index load per batch,
// no clamps/branches; max-free softmax; f16 packed logits + accumulator.
__global__ void attn4_bn(int N, const h16* __restrict__ XL, const h16* __restrict__ XR,
                         const float* __restrict__ att,
                         const int* __restrict__ rowstart, const int* __restrict__ deg,
                         const int* __restrict__ csr_src,
                         const float* __restrict__ gamma, const float* __restrict__ beta,
                         const float* __restrict__ mean, const float* __restrict__ var,
                         const float* __restrict__ bias, const float* __restrict__ resid,
                         float* __restrict__ out, h16* __restrict__ outb) {
    int d = blockIdx.x * (blockDim.x >> 6) + (threadIdx.x >> 6);
    int lane = threadIdx.x & 63;
    if (d >= N) return;
    half4v bv = *(const half4v*)(XR + (size_t)d * 256 + lane * 4);
    float4 wf = ((const float4*)att)[lane];
    half2v b0 = bv.xy, b1 = bv.zw;
    half2v w0 = { (h16)wf.x, (h16)wf.y };
    half2v w1 = { (h16)wf.z, (h16)wf.w };
    const h16 k02 = (h16)0.2f;

    auto edge_part = [&](half4v xv) -> h16 {
        half2v e0 = xv.xy + b0, e1 = xv.zw + b1;
        half2v l0 = __builtin_elementwise_max(e0, e0 * k02);
        half2v l1 = __builtin_elementwise_max(e1, e1 * k02);
        half2v qd = l0 * w0 + l1 * w1;
        return qd.x + qd.y;
    };

    int start = rowstart[d];
    int nreal = deg[d] + 1;              // self-loop included in CSR
    int npad  = (deg[d] + 4) & ~3;       // row padded to multiple of 4
    float l = 0.f;
    half2v acc0 = { (h16)0.f, (h16)0.f };
    half2v acc1 = { (h16)0.f, (h16)0.f };

    int4 iv = *(const int4*)(csr_src + start);      // npad >= 4 always
    for (int i = 0; i < npad; i += 4) {
        int4 cur = iv;
        if (i + 4 < npad) iv = *(const int4*)(csr_src + start + i + 4);
        half4v x0 = *(const half4v*)(XL + (size_t)cur.x * 256 + lane * 4);
        half4v x1 = *(const half4v*)(XL + (size_t)cur.y * 256 + lane * 4);
        half4v x2 = *(const half4v*)(XL + (size_t)cur.z * 256 + lane * 4);
        half4v x3 = *(const half4v*)(XL + (size_t)cur.w * 256 + lane * 4);
        half2v p01 = { edge_part(x0), edge_part(x1) };
        half2v p23 = { edge_part(x2), edge_part(x3) };
#pragma unroll
        for (int s = 1; s < 16; s <<= 1) {
            p01 += shfl_xor_h2(p01, s);
            p23 += shfl_xor_h2(p23, s);
        }
        int rem = nreal - i;
        float e0 = __expf((float)p01.x);
        float e1 = (rem > 1) ? __expf((float)p01.y) : 0.f;
        float e2 = (rem > 2) ? __expf((float)p23.x) : 0.f;
        float e3 = (rem > 3) ? __expf((float)p23.y) : 0.f;
        l += (e0 + e1) + (e2 + e3);
        h16 h0 = (h16)e0, h1 = (h16)e1, h2 = (h16)e2, h3 = (h16)e3;
        half2v eb0 = { h0, h0 }, eb1 = { h1, h1 }, eb2 = { h2, h2 }, eb3 = { h3, h3 };
        acc0 += eb0 * x0.xy; acc1 += eb0 * x0.zw;
        acc0 += eb1 * x1.xy; acc1 += eb1 * x1.zw;
        acc0 += eb2 * x2.xy; acc1 += eb2 * x2.zw;
        acc0 += eb3 * x3.xy; acc1 += eb3 * x3.zw;
    }
    float4 acc = { (float)acc0.x, (float)acc0.y, (float)acc1.x, (float)acc1.y };
    float inv = 1.f / l;
    float4 g  = ((const float4*)gamma)[lane];
    float4 be = ((const float4*)beta)[lane];
    float4 mu = ((const float4*)mean)[lane];
    float4 va = ((const float4*)var)[lane];
    float4 bi = ((const float4*)bias)[lane];
    float4 sc4, sh4;
    sc4.x = g.x * rsqrtf(va.x + 1e-5f); sh4.x = (bi.x - mu.x) * sc4.x + be.x;
    sc4.y = g.y * rsqrtf(va.y + 1e-5f); sh4.y = (bi.y - mu.y) * sc4.y + be.y;
    sc4.z = g.z * rsqrtf(va.z + 1e-5f); sh4.z = (bi.z - mu.z) * sc4.z + be.z;
    sc4.w = g.w * rsqrtf(va.w + 1e-5f); sh4.w = (bi.w - mu.w) * sc4.w + be.w;
    float4 o;
    o.x = fmaxf(acc.x * inv * sc4.x + sh4.x, 0.f);
    o.y = fmaxf(acc.y * inv * sc4.y + sh4.y, 0.f);
    o.z = fmaxf(acc.z * inv * sc4.z + sh4.z, 0.f);
    o.w = fmaxf(acc.w * inv * sc4.w + sh4.w, 0.f);
    if (resid) {
        float4 rv = *(const float4*)(resid + (size_t)d * 256 + lane * 4);
        o.x += rv.x; o.y += rv.y; o.z += rv.z; o.w += rv.w;
    }
    if (out) *(float4*)(out + (size_t)d * 256 + lane * 4) = o;
    if (outb) {
        half4v ob = { (h16)o.x, (h16)o.y, (h16)o.z, (h16)o.w };
        *(half4v*)(outb + (size_t)d * 256 + lane * 4) = ob;
    }
}

// ---- layer 2 projections from f16 input: 16 lanes/node, K=256 ----
__global__ void gemm2_wave(const h16* __restrict__ X, const float* __restrict__ Wl,
                           const float* __restrict__ Wr, float* __restrict__ xl2,
                           float* __restrict__ xr2, int N) {
    int t = blockIdx.x * blockDim.x + threadIdx.x;
    int n = t >> 4;
    int sl = t & 15;
    if (n >= N) return;
    const half4v* Xr = (const half4v*)(X + (size_t)n * 256);
    const float4* Wl4 = (const float4*)Wl;
    const float4* Wr4 = (const float4*)Wr;
    float l0 = 0.f, l1 = 0.f, r0 = 0.f, r1 = 0.f;
#pragma unroll
    for (int j = 0; j < 4; ++j) {
        int idx = sl + j * 16;
        half4v xh = Xr[idx];
        float4 xv = { (float)xh.x, (float)xh.y, (float)xh.z, (float)xh.w };
        float4 wa = Wl4[idx * 2];
        float4 wb = Wl4[idx * 2 + 1];
        l0 += xv.x * wa.x + xv.y * wa.z + xv.z * wb.x + xv.w * wb.z;
        l1 += xv.x * wa.y + xv.y * wa.w + xv.z * wb.y + xv.w * wb.w;
        wa = Wr4[idx * 2]; wb = Wr4[idx * 2 + 1];
        r0 += xv.x * wa.x + xv.y * wa.z + xv.z * wb.x + xv.w * wb.z;
        r1 += xv.x * wa.y + xv.y * wa.w + xv.z * wb.y + xv.w * wb.w;
    }
#pragma unroll
    for (int off = 1; off < 16; off <<= 1) {
        l0 += __shfl_xor(l0, off, 64);
        l1 += __shfl_xor(l1, off, 64);
        r0 += __shfl_xor(r0, off, 64);
        r1 += __shfl_xor(r1, off, 64);
    }
    if (sl == 0) {
        xl2[n * 2] = l0; xl2[n * 2 + 1] = l1;
        xr2[n * 2] = r0; xr2[n * 2 + 1] = r1;
    }
}

// ---- fused layer-2 attention (1 head, C=2) + log_softmax, 16 lanes/dst ----
// Padded CSR with self-loop included.
__global__ void attn1_16(int N, const float* __restrict__ xl2, const float* __restrict__ xr2,
                         const float* __restrict__ att, const float* __restrict__ bias,
                         const int* __restrict__ rowstart, const int* __restrict__ deg,
                         const int* __restrict__ csr_src, float* __restrict__ out) {
    int t = blockIdx.x * blockDim.x + threadIdx.x;
    int d = t >> 4, sl = t & 15;
    if (d >= N) return;
    float a0 = att[0], a1 = att[1];
    float2 xr = ((const float2*)xr2)[d];
    float b0 = xr.x, b1 = xr.y;
    int st = rowstart[d];
    int nreal = deg[d] + 1;
    int npad  = (deg[d] + 4) & ~3;
    float l = 0.f, ac0 = 0.f, ac1 = 0.f;
    for (int i = sl; i < npad; i += 16) {
        int s = csr_src[st + i];
        float2 xv = ((const float2*)xl2)[s];
        float q = lrelu(xv.x + b0) * a0 + lrelu(xv.y + b1) * a1;
        float e = (i < nreal) ? __expf(q) : 0.f;
        l += e; ac0 += e * xv.x; ac1 += e * xv.y;
    }
#pragma unroll
    for (int off = 1; off < 16; off <<= 1) {
        l   += __shfl_xor(l, off, 64);
        ac0 += __shfl_xor(ac0, off, 64);
        ac1 += __shfl_xor(ac1, off, 64);
    }
    if (sl == 0) {
        float inv = 1.f / l;
        float v0 = ac0 * inv + bias[0];
        float v1 = ac1 * inv + bias[1];
        float mx = fmaxf(v0, v1);
        float lse = mx + logf(__expf(v0 - mx) + __expf(v1 - mx));
        out[d * 2] = v0 - lse;
        out[d * 2 + 1] = v1 - lse;
    }
}

extern "C" void kernel_launch(void* const* d_in, const int* in_sizes, int n_in,
                              void* d_out, int out_size, void* d_ws, size_t ws_size,
                              hipStream_t stream) {
    const float* x        = (const float*)d_in[0];
    const int*   ei       = (const int*)  d_in[1];
    const float* W_in     = (const float*)d_in[2];
    const float* b_in     = (const float*)d_in[3];
    const float* Wl0      = (const float*)d_in[4];
    const float* Wr0      = (const float*)d_in[5];
    const float* att0     = (const float*)d_in[6];
    const float* bias0    = (const float*)d_in[7];
    const float* Wl1      = (const float*)d_in[8];
    const float* Wr1      = (const float*)d_in[9];
    const float* att1     = (const float*)d_in[10];
    const float* bias1    = (const float*)d_in[11];
    const float* Wl2      = (const float*)d_in[12];
    const float* Wr2      = (const float*)d_in[13];
    const float* att2     = (const float*)d_in[14];
    const float* bias2    = (const float*)d_in[15];
    const float* bn_gamma = (const float*)d_in[16];
    const float* bn_beta  = (const float*)d_in[17];
    const float* bn_mean  = (const float*)d_in[18];
    const float* bn_var   = (const float*)d_in[19];

    const int N  = in_sizes[0] / 128;
    const int E  = in_sizes[1] / 2;
    const int NB = (N + 255) / 256;

    float* ws = (float*)d_ws;
    size_t off = 0;
    float* C    = ws + off; off += (size_t)N * 256;     // layer0 out / residual (f32)
    float* XL2  = ws + off; off += (size_t)N * 2;
    float* XR2  = ws + off; off += (size_t)N * 2;
    h16* Ah   = (h16*)(ws + off); off += (size_t)N * 128;  // f16 xl [N,256]
    h16* Bh   = (h16*)(ws + off); off += (size_t)N * 128;  // f16 xr [N,256]
    h16* Ch   = (h16*)(ws + off); off += (size_t)N * 128;  // f16 copy of C
    h16* Dh   = (h16*)(ws + off); off += (size_t)N * 128;  // f16 layer1 out
    h16* H0h  = (h16*)(ws + off); off += (size_t)N * 32;   // f16 h0 [N,64]
    h16* xh   = (h16*)(ws + off); off += (size_t)N * 64;   // f16 x  [N,128]
    h16* Wp_in = (h16*)(ws + off); off += 4096;    // 128*64
    h16* Wp_l0 = (h16*)(ws + off); off += 8192;    // 64*256
    h16* Wp_r0 = (h16*)(ws + off); off += 8192;
    h16* Wp_l1 = (h16*)(ws + off); off += 32768;   // 256*256
    h16* Wp_r1 = (h16*)(ws + off); off += 32768;
    int* ip = (int*)(ws + off);
    int* deg      = ip;              ip += N;
    int* rowstart = ip;              ip += N;
    int* cursor   = ip;              ip += N;
    int* bsum     = ip;              ip += NB;
    int* csr_src  = ip;              ip += E + 4 * N + 64;  // padded CSR

    // ---- weight packing + x conversion + deg zeroing (one launch) ----
    const int PACK_T = 172032 + N * 32 + N;
    pack_all<<<(PACK_T + 255) / 256, 256, 0, stream>>>(
        W_in, Wl0, Wr0, Wl1, Wr1, Wp_in, Wp_l0, Wp_r0, Wp_l1, Wp_r1,
        (const float4*)x, (half4v*)xh, N * 32, deg, N);

    // ---- CSR build (parallel scan, padded rows incl. self-loop) ----
    hist_dst<<<(E + 255) / 256, 256, 0, stream>>>(ei, E, deg);
    scan_blk<<<NB, 256, 0, stream>>>(deg, rowstart, bsum, N);
    scan_off<<<1, 256, 0, stream>>>(bsum, NB);
    add_off<<<NB, 256, 0, stream>>>(bsum, deg, rowstart, cursor, csr_src, N);
    scatter_src<<<(E + 255) / 256, 256, 0, stream>>>(ei, E, cursor, csr_src);

    const int GBM = (N + 63) / 64;

    // h0 = relu(x @ W_in + b_in)  -> f16
    gemm_lds<4, 4, true, false><<<GBM, 256, 0, stream>>>(
        xh, Wp_in, nullptr, b_in, H0h, nullptr, N);

    // -------- layer 0 --------
    gemm_lds<2, 16, false, true><<<dim3(GBM, 2), 256, 0, stream>>>(
        H0h, Wp_l0, Wp_r0, nullptr, Ah, Bh, N);
    attn4_bn<<<(N + 3) / 4, 256, 0, stream>>>(N, Ah, Bh, att0, rowstart, deg, csr_src,
                                              bn_gamma, bn_beta, bn_mean, bn_var,
                                              bias0, nullptr, C, Ch);

    // -------- layer 1 (residual) --------
    gemm_lds<8, 16, false, true><<<dim3(GBM, 2), 256, 0, stream>>>(
        Ch, Wp_l1, Wp_r1, nullptr, Ah, Bh, N);
    attn4_bn<<<(N + 3) / 4, 256, 0, stream>>>(N, Ah, Bh, att1, rowstart, deg, csr_src,
                                              bn_gamma + 256, bn_beta + 256, bn_mean + 256,
                                              bn_var + 256, bias1, C, nullptr, Dh);

    // -------- layer 2 (1 head, C=2) + log_softmax --------
    gemm2_wave<<<(N * 16 + 255) / 256, 256, 0, stream>>>(Dh, Wl2, Wr2, XL2, XR2, N);
    attn1_16<<<(N * 16 + 255) / 256, 256, 0, stream>>>(N, XL2, XR2, att2, bias2,
                                                       rowstart, deg, csr_src, (float*)d_out);
}

// Round 15
// 405.494 us; speedup vs baseline: 1.0613x; 1.0457x over previous
//
#include <hip/hip_runtime.h>
#include <hip/hip_bf16.h>
#include <math.h>

// ---------------------------------------------------------------------------
// GATv2 3-layer GNN. CSR-by-dst padded to 4-edge batches (self-loop folded
// in); f16 MFMA GEMMs with double-buffered LDS staging; attention operand
// tables in fp8 e4m3 (halves the random-gather traffic; HW cvt on read),
// f16 packed logit/accumulator pipeline; BN/ReLU/residual fused.
// ---------------------------------------------------------------------------

using h16     = _Float16;
using half2v  = __attribute__((ext_vector_type(2))) h16;
using half4v  = __attribute__((ext_vector_type(4))) h16;
using half8   = __attribute__((ext_vector_type(8))) h16;
using floatx2 = __attribute__((ext_vector_type(2))) float;
using floatx4 = __attribute__((ext_vector_type(4))) float;

__device__ __forceinline__ float lrelu(float x) { return x > 0.f ? x : 0.2f * x; }

__device__ __forceinline__ half2v shfl_xor_h2(half2v v, int mask) {
    float f = __builtin_bit_cast(float, v);
    f = __shfl_xor(f, mask, 64);
    return __builtin_bit_cast(half2v, f);
}

// 4 fp8 (one dword) -> half4 via HW cvt
__device__ __forceinline__ half4v cvt_fp8x4(unsigned v) {
    floatx2 lo = __builtin_amdgcn_cvt_pk_f32_fp8((int)v, false);
    floatx2 hi = __builtin_amdgcn_cvt_pk_f32_fp8((int)v, true);
    half4v r = { (h16)lo.x, (h16)lo.y, (h16)hi.x, (h16)hi.y };
    return r;
}

// ---------------- CSR build ----------------
__global__ void hist_dst(const int* __restrict__ ei, int E, int* __restrict__ deg) {
    int e = blockIdx.x * blockDim.x + threadIdx.x;
    if (e < E) atomicAdd(&deg[ei[E + e]], 1);
}

// padded row length = ceil((deg+1)/4)*4  (self-loop + pads)
__global__ __launch_bounds__(256) void scan_blk(const int* __restrict__ deg,
                                                int* __restrict__ rowstart,
                                                int* __restrict__ bsum, int N) {
    int t = blockIdx.x * 256 + threadIdx.x;
    int lane = threadIdx.x & 63, wid = threadIdx.x >> 6;
    int v = (t < N) ? ((deg[t] + 4) & ~3) : 0;
    int x = v;
#pragma unroll
    for (int off = 1; off < 64; off <<= 1) {
        int y = __shfl_up(x, off, 64);
        if (lane >= off) x += y;
    }
    __shared__ int wsum[4];
    if (lane == 63) wsum[wid] = x;
    __syncthreads();
    int add = 0;
#pragma unroll
    for (int w = 0; w < 4; ++w) if (w < wid) add += wsum[w];
    int incl = x + add;
    if (t < N) rowstart[t] = incl - v;
    if (threadIdx.x == 255) bsum[blockIdx.x] = incl;
}

__global__ __launch_bounds__(256) void scan_off(int* __restrict__ bsum, int NB) {
    int t = threadIdx.x;
    int lane = t & 63, wid = t >> 6;
    int v = (t < NB) ? bsum[t] : 0;
    int x = v;
#pragma unroll
    for (int off = 1; off < 64; off <<= 1) {
        int y = __shfl_up(x, off, 64);
        if (lane >= off) x += y;
    }
    __shared__ int wsum[4];
    if (lane == 63) wsum[wid] = x;
    __syncthreads();
    int add = 0;
#pragma unroll
    for (int w = 0; w < 4; ++w) if (w < wid) add += wsum[w];
    if (t < NB) bsum[t] = x + add - v;
}

__global__ void add_off(const int* __restrict__ bsum, const int* __restrict__ deg,
                        int* __restrict__ rowstart, int* __restrict__ cursor,
                        int* __restrict__ csr_src, int N) {
    int t = blockIdx.x * 256 + threadIdx.x;
    if (t >= N) return;
    int r = rowstart[t] + bsum[blockIdx.x];
    rowstart[t] = r;
    cursor[t] = r;
    int dg = deg[t];
    int npad = (dg + 4) & ~3;
    for (int k = dg; k < npad; ++k) csr_src[r + k] = t;
}

__global__ void scatter_src(const int* __restrict__ ei, int E,
                            int* __restrict__ cursor, int* __restrict__ csr_src) {
    int e = blockIdx.x * blockDim.x + threadIdx.x;
    if (e >= E) return;
    int d = ei[E + e];
    int pos = atomicAdd(&cursor[d], 1);
    csr_src[pos] = ei[e];
}

// ------- weight packing + x conversion + deg zeroing (one launch) ---------
__device__ __forceinline__ void pack_one(const float* __restrict__ W,
                                         h16* __restrict__ Wp,
                                         int t, int K, int NC) {
    int j = t & 7;
    int l = (t >> 3) & 63;
    int rest = t >> 9;
    int NT = NC >> 4;
    int nt = rest % NT;
    int kc = rest / NT;
    int row = kc * 32 + (l >> 4) * 8 + j;
    int col = nt * 16 + (l & 15);
    Wp[t] = (h16)W[(size_t)row * NC + col];
}

__global__ void pack_all(const float* __restrict__ W_in,
                         const float* __restrict__ Wl0, const float* __restrict__ Wr0,
                         const float* __restrict__ Wl1, const float* __restrict__ Wr1,
                         h16* __restrict__ P_in,
                         h16* __restrict__ P_l0, h16* __restrict__ P_r0,
                         h16* __restrict__ P_l1, h16* __restrict__ P_r1,
                         const float4* __restrict__ x, half4v* __restrict__ xh, int n4,
                         int* __restrict__ deg, int N) {
    int t = blockIdx.x * blockDim.x + threadIdx.x;
    if (t < 8192)        pack_one(W_in, P_in, t, 128, 64);
    else if (t < 24576)  pack_one(Wl0, P_l0, t - 8192, 64, 256);
    else if (t < 40960)  pack_one(Wr0, P_r0, t - 24576, 64, 256);
    else if (t < 106496) pack_one(Wl1, P_l1, t - 40960, 256, 256);
    else if (t < 172032) pack_one(Wr1, P_r1, t - 106496, 256, 256);
    else if (t < 172032 + n4) {
        int u = t - 172032;
        float4 v = x[u];
        half4v o = { (h16)v.x, (h16)v.y, (h16)v.z, (h16)v.w };
        xh[u] = o;
    } else {
        int u = t - 172032 - n4;
        if (u < N) deg[u] = 0;
    }
}

// --------- MFMA GEMM, double-buffered LDS staging of W -----------------
// OUT8: write fp8 e4m3 (attention operand tables) instead of f16.
template<int KC, int NT, bool RELU, bool DUAL, bool OUT8>
__global__ __launch_bounds__(256) void gemm_lds(
        const h16* __restrict__ Xh,
        const h16* __restrict__ Wp0, const h16* __restrict__ Wp1,
        const float* __restrict__ bias,
        void* __restrict__ out0v, void* __restrict__ out1v, int M) {
    constexpr int K = KC * 32;
    constexpr int ldo = NT * 16;
    constexpr int CHUNK8 = NT * 64;
    constexpr int PER_THR = CHUNK8 / 256;
    __shared__ half8 wbuf[2][CHUNK8];

    const h16* Wp = (DUAL && blockIdx.y) ? Wp1 : Wp0;
    void* outv = (DUAL && blockIdx.y) ? out1v : out0v;
    const half8* WG = (const half8*)Wp;

    const int tid = threadIdx.x;
    const int wid = tid >> 6, lane = tid & 63;
    const int quad = lane >> 4, li = lane & 15;
    const int r0 = blockIdx.x * 64 + wid * 16;
    int arow = r0 + li; if (arow >= M) arow = M - 1;
    const half8* A8 = (const half8*)Xh + (size_t)arow * (K / 8) + quad;

    floatx4 acc[NT];
#pragma unroll
    for (int t = 0; t < NT; ++t) acc[t] = (floatx4){0.f, 0.f, 0.f, 0.f};

    half8 st[PER_THR];
#pragma unroll
    for (int i = 0; i < PER_THR; ++i) st[i] = WG[i * 256 + tid];
#pragma unroll
    for (int i = 0; i < PER_THR; ++i) wbuf[0][i * 256 + tid] = st[i];
    __syncthreads();

#pragma unroll
    for (int kc = 0; kc < KC; ++kc) {
        int cur = kc & 1;
        if (kc + 1 < KC) {
#pragma unroll
            for (int i = 0; i < PER_THR; ++i)
                st[i] = WG[(size_t)(kc + 1) * CHUNK8 + i * 256 + tid];
        }
        half8 a = A8[kc * 4];
#pragma unroll
        for (int nt = 0; nt < NT; ++nt) {
            half8 b = wbuf[cur][nt * 64 + lane];
            acc[nt] = __builtin_amdgcn_mfma_f32_16x16x32_f16(a, b, acc[nt], 0, 0, 0);
        }
        if (kc + 1 < KC) {
#pragma unroll
            for (int i = 0; i < PER_THR; ++i) wbuf[cur ^ 1][i * 256 + tid] = st[i];
        }
        __syncthreads();
    }

#pragma unroll
    for (int nt = 0; nt < NT; ++nt) {
#pragma unroll
        for (int reg = 0; reg < 4; ++reg) {
            int rr = r0 + quad * 4 + reg;
            if (rr >= M) continue;
            float v = acc[nt][reg];
            if (RELU) v = fmaxf(v + bias[nt * 16 + li], 0.f);
            if (OUT8) {
                int pk = __builtin_amdgcn_cvt_pk_fp8_f32(v, v, 0, false);
                ((unsigned char*)outv)[(size_t)rr * ldo + nt * 16 + li] = (unsigned char)pk;
            } else {
                ((h16*)outv)[(size_t)rr * ldo + nt * 16 + li] = (h16)v;
            }
        }
    }
}

// ---- fused 4-head attention + BN + ReLU (+residual), wave/dst, fp8 in -----
// Padded CSR (self-loop included): batch-4, int4 index load, fp8 gathers
// (HW cvt -> f16), max-free softmax, f16 packed logits + accumulator.
__global__ void attn4_bn(int N, const unsigned char* __restrict__ XL8,
                         const unsigned char* __restrict__ XR8,
                         const float* __restrict__ att,
                         const int* __restrict__ rowstart, const int* __restrict__ deg,
                         const int* __restrict__ csr_src,
                         const float* __restrict__ gamma, const float* __restrict__ beta,
                         const float* __restrict__ mean, const float* __restrict__ var,
                         const float* __restrict__ bias, const float* __restrict__ resid,
                         float* __restrict__ out, h16* __restrict__ outb) {
    int d = blockIdx.x * (blockDim.x >> 6) + (threadIdx.x >> 6);
    int lane = threadIdx.x & 63;
    if (d >= N) return;
    const unsigned* XL32 = (const unsigned*)XL8;
    unsigned bw = ((const unsigned*)(XR8 + (size_t)d * 256))[lane];
    half4v bv = cvt_fp8x4(bw);
    float4 wf = ((const float4*)att)[lane];
    half2v b0 = bv.xy, b1 = bv.zw;
    half2v w0 = { (h16)wf.x, (h16)wf.y };
    half2v w1 = { (h16)wf.z, (h16)wf.w };
    const h16 k02 = (h16)0.2f;

    auto edge_part = [&](half4v xv) -> h16 {
        half2v e0 = xv.xy + b0, e1 = xv.zw + b1;
        half2v l0 = __builtin_elementwise_max(e0, e0 * k02);
        half2v l1 = __builtin_elementwise_max(e1, e1 * k02);
        half2v qd = l0 * w0 + l1 * w1;
        return qd.x + qd.y;
    };

    int start = rowstart[d];
    int nreal = deg[d] + 1;              // self-loop included in CSR
    int npad  = (deg[d] + 4) & ~3;       // row padded to multiple of 4
    float l = 0.f;
    half2v acc0 = { (h16)0.f, (h16)0.f };
    half2v acc1 = { (h16)0.f, (h16)0.f };

    int4 iv = *(const int4*)(csr_src + start);      // npad >= 4 always
    for (int i = 0; i < npad; i += 4) {
        int4 cur = iv;
        if (i + 4 < npad) iv = *(const int4*)(csr_src + start + i + 4);
        unsigned v0 = XL32[(size_t)cur.x * 64 + lane];
        unsigned v1 = XL32[(size_t)cur.y * 64 + lane];
        unsigned v2 = XL32[(size_t)cur.z * 64 + lane];
        unsigned v3 = XL32[(size_t)cur.w * 64 + lane];
        half4v x0 = cvt_fp8x4(v0);
        half4v x1 = cvt_fp8x4(v1);
        half4v x2 = cvt_fp8x4(v2);
        half4v x3 = cvt_fp8x4(v3);
        half2v p01 = { edge_part(x0), edge_part(x1) };
        half2v p23 = { edge_part(x2), edge_part(x3) };
#pragma unroll
        for (int s = 1; s < 16; s <<= 1) {
            p01 += shfl_xor_h2(p01, s);
            p23 += shfl_xor_h2(p23, s);
        }
        int rem = nreal - i;
        float e0 = __expf((float)p01.x);
        float e1 = (rem > 1) ? __expf((float)p01.y) : 0.f;
        float e2 = (rem > 2) ? __expf((float)p23.x) : 0.f;
        float e3 = (rem > 3) ? __expf((float)p23.y) : 0.f;
        l += (e0 + e1) + (e2 + e3);
        h16 h0 = (h16)e0, h1 = (h16)e1, h2 = (h16)e2, h3 = (h16)e3;
        half2v eb0 = { h0, h0 }, eb1 = { h1, h1 }, eb2 = { h2, h2 }, eb3 = { h3, h3 };
        acc0 += eb0 * x0.xy; acc1 += eb0 * x0.zw;
        acc0 += eb1 * x1.xy; acc1 += eb1 * x1.zw;
        acc0 += eb2 * x2.xy; acc1 += eb2 * x2.zw;
        acc0 += eb3 * x3.xy; acc1 += eb3 * x3.zw;
    }
    float4 acc = { (float)acc0.x, (float)acc0.y, (float)acc1.x, (float)acc1.y };
    float inv = 1.f / l;
    float4 g  = ((const float4*)gamma)[lane];
    float4 be = ((const float4*)beta)[lane];
    float4 mu = ((const float4*)mean)[lane];
    float4 va = ((const float4*)var)[lane];
    float4 bi = ((const float4*)bias)[lane];
    float4 sc4, sh4;
    sc4.x = g.x * rsqrtf(va.x + 1e-5f); sh4.x = (bi.x - mu.x) * sc4.x + be.x;
    sc4.y = g.y * rsqrtf(va.y + 1e-5f); sh4.y = (bi.y - mu.y) * sc4.y + be.y;
    sc4.z = g.z * rsqrtf(va.z + 1e-5f); sh4.z = (bi.z - mu.z) * sc4.z + be.z;
    sc4.w = g.w * rsqrtf(va.w + 1e-5f); sh4.w = (bi.w - mu.w) * sc4.w + be.w;
    float4 o;
    o.x = fmaxf(acc.x * inv * sc4.x + sh4.x, 0.f);
    o.y = fmaxf(acc.y * inv * sc4.y + sh4.y, 0.f);
    o.z = fmaxf(acc.z * inv * sc4.z + sh4.z, 0.f);
    o.w = fmaxf(acc.w * inv * sc4.w + sh4.w, 0.f);
    if (resid) {
        float4 rv = *(const float4*)(resid + (size_t)d * 256 + lane * 4);
        o.x += rv.x; o.y += rv.y; o.z += rv.z; o.w += rv.w;
    }
    if (out) *(float4*)(out + (size_t)d * 256 + lane * 4) = o;
    if (outb) {
        half4v ob = { (h16)o.x, (h16)o.y, (h16)o.z, (h16)o.w };
        *(half4v*)(outb + (size_t)d * 256 + lane * 4) = ob;
    }
}

// ---- layer 2 projections from f16 input: 16 lanes/node, K=256 ----
__global__ void gemm2_wave(const h16* __restrict__ X, const float* __restrict__ Wl,
                           const float* __restrict__ Wr, float* __restrict__ xl2,
                           float* __restrict__ xr2, int N) {
    int t = blockIdx.x * blockDim.x + threadIdx.x;
    int n = t >> 4;
    int sl = t & 15;
    if (n >= N) return;
    const half4v* Xr = (const half4v*)(X + (size_t)n * 256);
    const float4* Wl4 = (const float4*)Wl;
    const float4* Wr4 = (const float4*)Wr;
    float l0 = 0.f, l1 = 0.f, r0 = 0.f, r1 = 0.f;
#pragma unroll
    for (int j = 0; j < 4; ++j) {
        int idx = sl + j * 16;
        half4v xh = Xr[idx];
        float4 xv = { (float)xh.x, (float)xh.y, (float)xh.z, (float)xh.w };
        float4 wa = Wl4[idx * 2];
        float4 wb = Wl4[idx * 2 + 1];
        l0 += xv.x * wa.x + xv.y * wa.z + xv.z * wb.x + xv.w * wb.z;
        l1 += xv.x * wa.y + xv.y * wa.w + xv.z * wb.y + xv.w * wb.w;
        wa = Wr4[idx * 2]; wb = Wr4[idx * 2 + 1];
        r0 += xv.x * wa.x + xv.y * wa.z + xv.z * wb.x + xv.w * wb.z;
        r1 += xv.x * wa.y + xv.y * wa.w + xv.z * wb.y + xv.w * wb.w;
    }
#pragma unroll
    for (int off = 1; off < 16; off <<= 1) {
        l0 += __shfl_xor(l0, off, 64);
        l1 += __shfl_xor(l1, off, 64);
        r0 += __shfl_xor(r0, off, 64);
        r1 += __shfl_xor(r1, off, 64);
    }
    if (sl == 0) {
        xl2[n * 2] = l0; xl2[n * 2 + 1] = l1;
        xr2[n * 2] = r0; xr2[n * 2 + 1] = r1;
    }
}

// ---- fused layer-2 attention (1 head, C=2) + log_softmax, 16 lanes/dst ----
__global__ void attn1_16(int N, const float* __restrict__ xl2, const float* __restrict__ xr2,
                         const float* __restrict__ att, const float* __restrict__ bias,
                         const int* __restrict__ rowstart, const int* __restrict__ deg,
                         const int* __restrict__ csr_src, float* __restrict__ out) {
    int t = blockIdx.x * blockDim.x + threadIdx.x;
    int d = t >> 4, sl = t & 15;
    if (d >= N) return;
    float a0 = att[0], a1 = att[1];
    float2 xr = ((const float2*)xr2)[d];
    float b0 = xr.x, b1 = xr.y;
    int st = rowstart[d];
    int nreal = deg[d] + 1;
    int npad  = (deg[d] + 4) & ~3;
    float l = 0.f, ac0 = 0.f, ac1 = 0.f;
    for (int i = sl; i < npad; i += 16) {
        int s = csr_src[st + i];
        float2 xv = ((const float2*)xl2)[s];
        float q = lrelu(xv.x + b0) * a0 + lrelu(xv.y + b1) * a1;
        float e = (i < nreal) ? __expf(q) : 0.f;
        l += e; ac0 += e * xv.x; ac1 += e * xv.y;
    }
#pragma unroll
    for (int off = 1; off < 16; off <<= 1) {
        l   += __shfl_xor(l, off, 64);
        ac0 += __shfl_xor(ac0, off, 64);
        ac1 += __shfl_xor(ac1, off, 64);
    }
    if (sl == 0) {
        float inv = 1.f / l;
        float v0 = ac0 * inv + bias[0];
        float v1 = ac1 * inv + bias[1];
        float mx = fmaxf(v0, v1);
        float lse = mx + logf(__expf(v0 - mx) + __expf(v1 - mx));
        out[d * 2] = v0 - lse;
        out[d * 2 + 1] = v1 - lse;
    }
}

extern "C" void kernel_launch(void* const* d_in, const int* in_sizes, int n_in,
                              void* d_out, int out_size, void* d_ws, size_t ws_size,
                              hipStream_t stream) {
    const float* x        = (const float*)d_in[0];
    const int*   ei       = (const int*)  d_in[1];
    const float* W_in     = (const float*)d_in[2];
    const float* b_in     = (const float*)d_in[3];
    const float* Wl0      = (const float*)d_in[4];
    const float* Wr0      = (const float*)d_in[5];
    const float* att0     = (const float*)d_in[6];
    const float* bias0    = (const float*)d_in[7];
    const float* Wl1      = (const float*)d_in[8];
    const float* Wr1      = (const float*)d_in[9];
    const float* att1     = (const float*)d_in[10];
    const float* bias1    = (const float*)d_in[11];
    const float* Wl2      = (const float*)d_in[12];
    const float* Wr2      = (const float*)d_in[13];
    const float* att2     = (const float*)d_in[14];
    const float* bias2    = (const float*)d_in[15];
    const float* bn_gamma = (const float*)d_in[16];
    const float* bn_beta  = (const float*)d_in[17];
    const float* bn_mean  = (const float*)d_in[18];
    const float* bn_var   = (const float*)d_in[19];

    const int N  = in_sizes[0] / 128;
    const int E  = in_sizes[1] / 2;
    const int NB = (N + 255) / 256;

    float* ws = (float*)d_ws;
    size_t off = 0;
    float* C    = ws + off; off += (size_t)N * 256;     // layer0 out / residual (f32)
    float* XL2  = ws + off; off += (size_t)N * 2;
    float* XR2  = ws + off; off += (size_t)N * 2;
    unsigned char* A8 = (unsigned char*)(ws + off); off += (size_t)N * 64;   // fp8 xl [N,256]
    unsigned char* B8 = (unsigned char*)(ws + off); off += (size_t)N * 64;   // fp8 xr [N,256]
    h16* Ch   = (h16*)(ws + off); off += (size_t)N * 128;  // f16 layer0 out (GEMM A input)
    h16* Dh   = (h16*)(ws + off); off += (size_t)N * 128;  // f16 layer1 out
    h16* H0h  = (h16*)(ws + off); off += (size_t)N * 32;   // f16 h0 [N,64]
    h16* xh   = (h16*)(ws + off); off += (size_t)N * 64;   // f16 x  [N,128]
    h16* Wp_in = (h16*)(ws + off); off += 4096;    // 128*64
    h16* Wp_l0 = (h16*)(ws + off); off += 8192;    // 64*256
    h16* Wp_r0 = (h16*)(ws + off); off += 8192;
    h16* Wp_l1 = (h16*)(ws + off); off += 32768;   // 256*256
    h16* Wp_r1 = (h16*)(ws + off); off += 32768;
    int* ip = (int*)(ws + off);
    int* deg      = ip;              ip += N;
    int* rowstart = ip;              ip += N;
    int* cursor   = ip;              ip += N;
    int* bsum     = ip;              ip += NB;
    int* csr_src  = ip;              ip += E + 4 * N + 64;  // padded CSR

    // ---- weight packing + x conversion + deg zeroing (one launch) ----
    const int PACK_T = 172032 + N * 32 + N;
    pack_all<<<(PACK_T + 255) / 256, 256, 0, stream>>>(
        W_in, Wl0, Wr0, Wl1, Wr1, Wp_in, Wp_l0, Wp_r0, Wp_l1, Wp_r1,
        (const float4*)x, (half4v*)xh, N * 32, deg, N);

    // ---- CSR build (parallel scan, padded rows incl. self-loop) ----
    hist_dst<<<(E + 255) / 256, 256, 0, stream>>>(ei, E, deg);
    scan_blk<<<NB, 256, 0, stream>>>(deg, rowstart, bsum, N);
    scan_off<<<1, 256, 0, stream>>>(bsum, NB);
    add_off<<<NB, 256, 0, stream>>>(bsum, deg, rowstart, cursor, csr_src, N);
    scatter_src<<<(E + 255) / 256, 256, 0, stream>>>(ei, E, cursor, csr_src);

    const int GBM = (N + 63) / 64;

    // h0 = relu(x @ W_in + b_in)  -> f16
    gemm_lds<4, 4, true, false, false><<<GBM, 256, 0, stream>>>(
        xh, Wp_in, nullptr, b_in, H0h, nullptr, N);

    // -------- layer 0 --------
    gemm_lds<2, 16, false, true, true><<<dim3(GBM, 2), 256, 0, stream>>>(
        H0h, Wp_l0, Wp_r0, nullptr, A8, B8, N);
    attn4_bn<<<(N + 3) / 4, 256, 0, stream>>>(N, A8, B8, att0, rowstart, deg, csr_src,
                                              bn_gamma, bn_beta, bn_mean, bn_var,
                                              bias0, nullptr, C, Ch);

    // -------- layer 1 (residual) --------
    gemm_lds<8, 16, false, true, true><<<dim3(GBM, 2), 256, 0, stream>>>(
        Ch, Wp_l1, Wp_r1, nullptr, A8, B8, N);
    attn4_bn<<<(N + 3) / 4, 256, 0, stream>>>(N, A8, B8, att1, rowstart, deg, csr_src,
                                              bn_gamma + 256, bn_beta + 256, bn_mean + 256,
                                              bn_var + 256, bias1, C, nullptr, Dh);

    // -------- layer 2 (1 head, C=2) + log_softmax --------
    gemm2_wave<<<(N * 16 + 255) / 256, 256, 0, stream>>>(Dh, Wl2, Wr2, XL2, XR2, N);
    attn1_16<<<(N * 16 + 255) / 256, 256, 0, stream>>>(N, XL2, XR2, att2, bias2,
                                                       rowstart, deg, csr_src, (float*)d_out);
}